// Round 1
// baseline (162.769 us; speedup 1.0000x reference)
//
#include <hip/hip_runtime.h>

// Selective scan (Mamba-style), fp32.
// x:(B,d,L) deltaA/deltaB:(B,d,L,n) C:(B,n,L) D:(d,)  ->  y:(B,d,L)
// B=64, d_inner=384, L=197, n=16.
//
// Design: 16 lanes per (b,d) pair, lane = state index n. h[n] lives in a
// register. deltaA/deltaB reads are 64B-contiguous per group (coalesced).
// y_t = 16-lane butterfly reduce of h[n]*C[n,t]. C staged in LDS per block
// (its global layout is n-major -> strided; LDS fixes that, and it's reused
// by all 16 d's in the block).

#define B_   64
#define DIN  384
#define L_   197
#define N_   16
#define GROUPS_PER_BLOCK 16   // 256 threads / 16 lanes

__global__ __launch_bounds__(256)
void ssm_scan_kernel(const float* __restrict__ x,
                     const float* __restrict__ dA,
                     const float* __restrict__ dB,
                     const float* __restrict__ C,
                     const float* __restrict__ D,
                     float* __restrict__ y)
{
    __shared__ float Cs[N_ * L_];   // 12608 B, one b-slice of C

    const int tid = threadIdx.x;
    const int b   = blockIdx.y;

    // Stage C[b,:,:] (N_*L_ contiguous floats) into LDS, linear copy.
    const float* Cg = C + (size_t)b * (N_ * L_);
    for (int i = tid; i < N_ * L_; i += 256) Cs[i] = Cg[i];
    __syncthreads();

    const int grp = tid >> 4;        // which (b,d) within block
    const int n   = tid & 15;        // state index
    const int d   = blockIdx.x * GROUPS_PER_BLOCK + grp;

    const size_t bd = (size_t)b * DIN + d;
    const float* pA = dA + bd * (size_t)(L_ * N_) + n;
    const float* pB = dB + bd * (size_t)(L_ * N_) + n;
    const float* px = x  + bd * L_;
    float*       py = y  + bd * L_;
    const float  Dd = D[d];
    const float* Cn = Cs + n * L_;   // bank-conflict-free: (5n+t)%32 distinct

    float h = 0.0f;
    int t = 0;

    // main loop, unrolled by 4 for memory-level parallelism
    for (; t + 4 <= L_; t += 4) {
        const float a0 = pA[(t+0)*N_], a1 = pA[(t+1)*N_];
        const float a2 = pA[(t+2)*N_], a3 = pA[(t+3)*N_];
        const float g0 = pB[(t+0)*N_], g1 = pB[(t+1)*N_];
        const float g2 = pB[(t+2)*N_], g3 = pB[(t+3)*N_];
        const float x0 = px[t+0], x1 = px[t+1], x2 = px[t+2], x3 = px[t+3];
        const float c0 = Cn[t+0], c1 = Cn[t+1], c2 = Cn[t+2], c3 = Cn[t+3];

        h = fmaf(a0, h, g0 * x0);  float p0 = h * c0;
        h = fmaf(a1, h, g1 * x1);  float p1 = h * c1;
        h = fmaf(a2, h, g2 * x2);  float p2 = h * c2;
        h = fmaf(a3, h, g3 * x3);  float p3 = h * c3;

        // 16-lane butterfly sums (4 independent chains, ILP-friendly)
        #pragma unroll
        for (int m = 1; m < 16; m <<= 1) {
            p0 += __shfl_xor(p0, m);
            p1 += __shfl_xor(p1, m);
            p2 += __shfl_xor(p2, m);
            p3 += __shfl_xor(p3, m);
        }

        if (n == 0) {
            py[t+0] = fmaf(x0, Dd, p0);
            py[t+1] = fmaf(x1, Dd, p1);
            py[t+2] = fmaf(x2, Dd, p2);
            py[t+3] = fmaf(x3, Dd, p3);
        }
    }

    // tail (L_ = 197 = 49*4 + 1)
    for (; t < L_; ++t) {
        const float a  = pA[t*N_];
        const float g  = pB[t*N_];
        const float xv = px[t];
        h = fmaf(a, h, g * xv);
        float p = h * Cn[t];
        #pragma unroll
        for (int m = 1; m < 16; m <<= 1) p += __shfl_xor(p, m);
        if (n == 0) py[t] = fmaf(xv, Dd, p);
    }
}

extern "C" void kernel_launch(void* const* d_in, const int* in_sizes, int n_in,
                              void* d_out, int out_size, void* d_ws, size_t ws_size,
                              hipStream_t stream) {
    const float* x  = (const float*)d_in[0];
    const float* dA = (const float*)d_in[1];
    const float* dB = (const float*)d_in[2];
    const float* C  = (const float*)d_in[3];
    const float* D  = (const float*)d_in[4];
    float* y = (float*)d_out;

    dim3 grid(DIN / GROUPS_PER_BLOCK, B_);   // (24, 64)
    dim3 block(256);
    ssm_scan_kernel<<<grid, block, 0, stream>>>(x, dA, dB, C, D, y);
}

// Round 2
// 156.946 us; speedup vs baseline: 1.0371x; 1.0371x over previous
//
#include <hip/hip_runtime.h>

// Selective scan (Mamba-style), fp32.
// x:(B,d,L) deltaA/deltaB:(B,d,L,n) C:(B,n,L) D:(d,)  ->  y:(B,d,L)
// B=64, d_inner=384, L=197, n=16.
//
// Round-2 design: 4 lanes per (b,d), each lane owns 4 states (n = 4*n4..4*n4+3).
// dA/dB read as float4 (global_load_dwordx4; 64B contiguous per group).
// C staged transposed in LDS -> one ds_read_b128 per step (broadcast, no
// conflicts). 2-stage butterfly for the n-reduction. 128-thread blocks,
// grid (12,64)=768 blocks = exactly 3 blocks/CU (even).

#define B_   64
#define DIN  384
#define L_   197
#define N_   16
#define GRP_PER_BLOCK 32   // 128 threads / 4 lanes per group

__global__ __launch_bounds__(128)
void ssm_scan4(const float* __restrict__ x,
               const float* __restrict__ dA,
               const float* __restrict__ dB,
               const float* __restrict__ C,
               const float* __restrict__ D,
               float* __restrict__ y)
{
    __shared__ float Cs[L_ * N_];   // transposed: Cs[t*16 + n], 12608 B

    const int tid = threadIdx.x;
    const int b   = blockIdx.y;

    // Stage C[b,:,:] transposed. Global reads linear (coalesced); LDS writes
    // scattered but this runs once per block.
    const float* Cg = C + (size_t)b * (N_ * L_);
    for (int i = tid; i < N_ * L_; i += 128) {
        const int n = i / L_;          // const-div -> magic mul
        const int t = i - n * L_;
        Cs[t * N_ + n] = Cg[i];
    }
    __syncthreads();

    const int grp = tid >> 2;          // group within block (one (b,d))
    const int n4  = tid & 3;           // which 4-state slice
    const int d   = blockIdx.x * GRP_PER_BLOCK + grp;

    const size_t bd = (size_t)b * DIN + d;
    // float4 view: element t of dA for this lane = pA[t*4]
    const float4* pA = (const float4*)dA + bd * (size_t)(L_ * 4) + n4;
    const float4* pB = (const float4*)dB + bd * (size_t)(L_ * 4) + n4;
    const float*  px = x + bd * L_;
    float*        py = y + bd * L_;
    const float   Dd = D[d];

    float h0 = 0.f, h1 = 0.f, h2 = 0.f, h3 = 0.f;
    int t = 0;

    // main loop: 4 time-steps per body (L_ = 4*49 + 1)
    for (; t + 4 <= L_; t += 4) {
        // all loads independent of h -> issued up front, deep in flight
        const float4 a0 = pA[(t+0)*4], a1 = pA[(t+1)*4];
        const float4 a2 = pA[(t+2)*4], a3 = pA[(t+3)*4];
        const float4 g0 = pB[(t+0)*4], g1 = pB[(t+1)*4];
        const float4 g2 = pB[(t+2)*4], g3 = pB[(t+3)*4];
        const float  x0 = px[t+0], x1 = px[t+1], x2 = px[t+2], x3 = px[t+3];
        const float4 c0 = *(const float4*)(Cs + (t+0)*N_ + n4*4);
        const float4 c1 = *(const float4*)(Cs + (t+1)*N_ + n4*4);
        const float4 c2 = *(const float4*)(Cs + (t+2)*N_ + n4*4);
        const float4 c3 = *(const float4*)(Cs + (t+3)*N_ + n4*4);

        h0 = fmaf(a0.x, h0, g0.x * x0);
        h1 = fmaf(a0.y, h1, g0.y * x0);
        h2 = fmaf(a0.z, h2, g0.z * x0);
        h3 = fmaf(a0.w, h3, g0.w * x0);
        float p0 = fmaf(h0, c0.x, fmaf(h1, c0.y, fmaf(h2, c0.z, h3 * c0.w)));

        h0 = fmaf(a1.x, h0, g1.x * x1);
        h1 = fmaf(a1.y, h1, g1.y * x1);
        h2 = fmaf(a1.z, h2, g1.z * x1);
        h3 = fmaf(a1.w, h3, g1.w * x1);
        float p1 = fmaf(h0, c1.x, fmaf(h1, c1.y, fmaf(h2, c1.z, h3 * c1.w)));

        h0 = fmaf(a2.x, h0, g2.x * x2);
        h1 = fmaf(a2.y, h1, g2.y * x2);
        h2 = fmaf(a2.z, h2, g2.z * x2);
        h3 = fmaf(a2.w, h3, g2.w * x2);
        float p2 = fmaf(h0, c2.x, fmaf(h1, c2.y, fmaf(h2, c2.z, h3 * c2.w)));

        h0 = fmaf(a3.x, h0, g3.x * x3);
        h1 = fmaf(a3.y, h1, g3.y * x3);
        h2 = fmaf(a3.z, h2, g3.z * x3);
        h3 = fmaf(a3.w, h3, g3.w * x3);
        float p3 = fmaf(h0, c3.x, fmaf(h1, c3.y, fmaf(h2, c3.z, h3 * c3.w)));

        // 2-stage butterfly within the 4-lane group; sum lands in all 4 lanes
        p0 += __shfl_xor(p0, 1);  p0 += __shfl_xor(p0, 2);
        p1 += __shfl_xor(p1, 1);  p1 += __shfl_xor(p1, 2);
        p2 += __shfl_xor(p2, 1);  p2 += __shfl_xor(p2, 2);
        p3 += __shfl_xor(p3, 1);  p3 += __shfl_xor(p3, 2);

        // distributed store: lane n4 writes element t+n4 (16B contiguous/group)
        const float y0 = fmaf(x0, Dd, p0);
        const float y1 = fmaf(x1, Dd, p1);
        const float y2 = fmaf(x2, Dd, p2);
        const float y3 = fmaf(x3, Dd, p3);
        float yv = (n4 == 0) ? y0 : (n4 == 1) ? y1 : (n4 == 2) ? y2 : y3;
        py[t + n4] = yv;
    }

    // tail (t = 196)
    for (; t < L_; ++t) {
        const float4 a = pA[t*4];
        const float4 g = pB[t*4];
        const float  xv = px[t];
        const float4 c = *(const float4*)(Cs + t*N_ + n4*4);
        h0 = fmaf(a.x, h0, g.x * xv);
        h1 = fmaf(a.y, h1, g.y * xv);
        h2 = fmaf(a.z, h2, g.z * xv);
        h3 = fmaf(a.w, h3, g.w * xv);
        float p = fmaf(h0, c.x, fmaf(h1, c.y, fmaf(h2, c.z, h3 * c.w)));
        p += __shfl_xor(p, 1);
        p += __shfl_xor(p, 2);
        if (n4 == 0) py[t] = fmaf(xv, Dd, p);
    }
}

extern "C" void kernel_launch(void* const* d_in, const int* in_sizes, int n_in,
                              void* d_out, int out_size, void* d_ws, size_t ws_size,
                              hipStream_t stream) {
    const float* x  = (const float*)d_in[0];
    const float* dA = (const float*)d_in[1];
    const float* dB = (const float*)d_in[2];
    const float* C  = (const float*)d_in[3];
    const float* D  = (const float*)d_in[4];
    float* y = (float*)d_out;

    dim3 grid(DIN / GRP_PER_BLOCK, B_);   // (12, 64) = 768 blocks
    dim3 block(128);
    ssm_scan4<<<grid, block, 0, stream>>>(x, dA, dB, C, D, y);
}

// Round 3
// 150.848 us; speedup vs baseline: 1.0790x; 1.0404x over previous
//
#include <hip/hip_runtime.h>

// Selective scan (Mamba-style), fp32.
// x:(B,d,L) deltaA/deltaB:(B,d,L,n) C:(B,n,L) D:(d,)  ->  y:(B,d,L)
// B=64, d_inner=384, L=197, n=16.
//
// Round-3: same 4-lanes-per-(b,d) decomposition as round 2, but with an
// EXPLICIT depth-2 software pipeline (3 named register buffer sets, loop
// unrolled x3 for static renaming). Round-2's VGPR_Count=40 showed the
// compiler serialized the loads; here ~2 bodies (18KB/wave) stay in flight.

#define B_   64
#define DIN  384
#define L_   197
#define N_   16
#define GRP_PER_BLOCK 32   // 128 threads / 4 lanes per group

__global__ __launch_bounds__(128, 1)
void ssm_scan_pipe(const float* __restrict__ x,
                   const float* __restrict__ dA,
                   const float* __restrict__ dB,
                   const float* __restrict__ C,
                   const float* __restrict__ D,
                   float* __restrict__ y)
{
    __shared__ __align__(16) float Cs[L_ * N_];   // transposed: Cs[t*16+n]

    const int tid = threadIdx.x;
    const int b   = blockIdx.y;

    // Stage C[b,:,:] transposed (once per block; bank conflicts here are noise).
    const float* Cg = C + (size_t)b * (N_ * L_);
    for (int i = tid; i < N_ * L_; i += 128) {
        const int n = i / L_;
        const int t = i - n * L_;
        Cs[t * N_ + n] = Cg[i];
    }
    __syncthreads();

    const int grp = tid >> 2;
    const int n4  = tid & 3;
    const int d   = blockIdx.x * GRP_PER_BLOCK + grp;

    const size_t bd = (size_t)b * DIN + d;
    const float4* pA = (const float4*)dA + bd * (size_t)(L_ * 4) + n4;
    const float4* pB = (const float4*)dB + bd * (size_t)(L_ * 4) + n4;
    const float*  px = x + bd * L_;
    float*        py = y + bd * L_;
    const float   Dd = D[d];
    const float*  CsL = Cs + n4 * 4;    // lane's C slice base (16B aligned)

    float h0 = 0.f, h1 = 0.f, h2 = 0.f, h3 = 0.f;

    // ---- named register buffer sets (no runtime indexing -> stays in VGPRs)
#define DECLBUF(Bu) float4 Bu##a0,Bu##a1,Bu##a2,Bu##a3, Bu##g0,Bu##g1,Bu##g2,Bu##g3, \
                            Bu##c0,Bu##c1,Bu##c2,Bu##c3; \
                    float  Bu##x0,Bu##x1,Bu##x2,Bu##x3;
    DECLBUF(B0) DECLBUF(B1) DECLBUF(B2)

#define LOADB(Bu, k) do { const int tt=(k)*4; \
    Bu##a0=pA[(tt+0)*4]; Bu##a1=pA[(tt+1)*4]; Bu##a2=pA[(tt+2)*4]; Bu##a3=pA[(tt+3)*4]; \
    Bu##g0=pB[(tt+0)*4]; Bu##g1=pB[(tt+1)*4]; Bu##g2=pB[(tt+2)*4]; Bu##g3=pB[(tt+3)*4]; \
    Bu##x0=px[tt+0]; Bu##x1=px[tt+1]; Bu##x2=px[tt+2]; Bu##x3=px[tt+3]; \
    Bu##c0=*(const float4*)(CsL+(tt+0)*N_); Bu##c1=*(const float4*)(CsL+(tt+1)*N_); \
    Bu##c2=*(const float4*)(CsL+(tt+2)*N_); Bu##c3=*(const float4*)(CsL+(tt+3)*N_); \
  } while(0)

#define COMPB(Bu, k) do { const int tt=(k)*4; \
    h0=fmaf(Bu##a0.x,h0,Bu##g0.x*Bu##x0); h1=fmaf(Bu##a0.y,h1,Bu##g0.y*Bu##x0); \
    h2=fmaf(Bu##a0.z,h2,Bu##g0.z*Bu##x0); h3=fmaf(Bu##a0.w,h3,Bu##g0.w*Bu##x0); \
    float p0=fmaf(h0,Bu##c0.x,fmaf(h1,Bu##c0.y,fmaf(h2,Bu##c0.z,h3*Bu##c0.w))); \
    h0=fmaf(Bu##a1.x,h0,Bu##g1.x*Bu##x1); h1=fmaf(Bu##a1.y,h1,Bu##g1.y*Bu##x1); \
    h2=fmaf(Bu##a1.z,h2,Bu##g1.z*Bu##x1); h3=fmaf(Bu##a1.w,h3,Bu##g1.w*Bu##x1); \
    float p1=fmaf(h0,Bu##c1.x,fmaf(h1,Bu##c1.y,fmaf(h2,Bu##c1.z,h3*Bu##c1.w))); \
    h0=fmaf(Bu##a2.x,h0,Bu##g2.x*Bu##x2); h1=fmaf(Bu##a2.y,h1,Bu##g2.y*Bu##x2); \
    h2=fmaf(Bu##a2.z,h2,Bu##g2.z*Bu##x2); h3=fmaf(Bu##a2.w,h3,Bu##g2.w*Bu##x2); \
    float p2=fmaf(h0,Bu##c2.x,fmaf(h1,Bu##c2.y,fmaf(h2,Bu##c2.z,h3*Bu##c2.w))); \
    h0=fmaf(Bu##a3.x,h0,Bu##g3.x*Bu##x3); h1=fmaf(Bu##a3.y,h1,Bu##g3.y*Bu##x3); \
    h2=fmaf(Bu##a3.z,h2,Bu##g3.z*Bu##x3); h3=fmaf(Bu##a3.w,h3,Bu##g3.w*Bu##x3); \
    float p3=fmaf(h0,Bu##c3.x,fmaf(h1,Bu##c3.y,fmaf(h2,Bu##c3.z,h3*Bu##c3.w))); \
    p0+=__shfl_xor(p0,1); p1+=__shfl_xor(p1,1); p2+=__shfl_xor(p2,1); p3+=__shfl_xor(p3,1); \
    p0+=__shfl_xor(p0,2); p1+=__shfl_xor(p1,2); p2+=__shfl_xor(p2,2); p3+=__shfl_xor(p3,2); \
    const float yv = (n4==0)?fmaf(Bu##x0,Dd,p0):(n4==1)?fmaf(Bu##x1,Dd,p1): \
                     (n4==2)?fmaf(Bu##x2,Dd,p2):fmaf(Bu##x3,Dd,p3); \
    py[tt+n4]=yv; \
  } while(0)

    // 49 full 4-step bodies (t=0..195), then a 1-step tail (t=196).
    // Pipeline: preload bodies 0,1; loop computes k and loads k+2.
    LOADB(B0, 0);
    LOADB(B1, 1);

    // Unrolled x3 rotation: bodies 0..44 computed here, loads up to 46.
    for (int k = 0; k <= 42; k += 3) {
        LOADB(B2, k+2);  COMPB(B0, k);
        LOADB(B0, k+3);  COMPB(B1, k+1);
        LOADB(B1, k+4);  COMPB(B2, k+2);
    }
    // Epilogue: computes 45..48, loads 47,48.   (45%3=0, 46%3=1, 47%3=2, 48%3=0)
    LOADB(B2, 47);  COMPB(B0, 45);
    LOADB(B0, 48);  COMPB(B1, 46);
    COMPB(B2, 47);
    COMPB(B0, 48);

    // tail step t = 196
    {
        const int t = 196;
        const float4 a = pA[t*4];
        const float4 g = pB[t*4];
        const float  xv = px[t];
        const float4 c = *(const float4*)(CsL + t*N_);
        h0 = fmaf(a.x, h0, g.x * xv);
        h1 = fmaf(a.y, h1, g.y * xv);
        h2 = fmaf(a.z, h2, g.z * xv);
        h3 = fmaf(a.w, h3, g.w * xv);
        float p = fmaf(h0, c.x, fmaf(h1, c.y, fmaf(h2, c.z, h3 * c.w)));
        p += __shfl_xor(p, 1);
        p += __shfl_xor(p, 2);
        if (n4 == 0) py[t] = fmaf(xv, Dd, p);
    }
}

extern "C" void kernel_launch(void* const* d_in, const int* in_sizes, int n_in,
                              void* d_out, int out_size, void* d_ws, size_t ws_size,
                              hipStream_t stream) {
    const float* x  = (const float*)d_in[0];
    const float* dA = (const float*)d_in[1];
    const float* dB = (const float*)d_in[2];
    const float* C  = (const float*)d_in[3];
    const float* D  = (const float*)d_in[4];
    float* y = (float*)d_out;

    dim3 grid(DIN / GRP_PER_BLOCK, B_);   // (12, 64) = 768 blocks
    dim3 block(128);
    ssm_scan_pipe<<<grid, block, 0, stream>>>(x, dA, dB, C, D, y);
}

// Round 4
// 149.000 us; speedup vs baseline: 1.0924x; 1.0124x over previous
//
#include <hip/hip_runtime.h>

// Selective scan (Mamba-style), fp32.  x:(B,d,L) dA/dB:(B,d,L,n) C:(B,n,L) D:(d,) -> y:(B,d,L)
// B=64 d=384 L=197 n=16.
//
// Round-4: DMA-staged tiles (global_load_lds) + counted vmcnt prefetch.
// 1 wave per block; wave = 16 (b,d) pairs x 4 lanes; lane owns 4 states.
// Per 8-step tile: 18 LDS-DMA ops staged one tile ahead; s_waitcnt vmcnt(18)
// guarantees tile k resident while tile k+1 stays in flight (HW-enforced MLP).
// Per step: 3x ds_read_b128 (A,B,C) + 1 b32 (x); n-reduction via 2 DPP
// quad-perm adds (VALU pipe, no LDS shuffle ops).

#define B_    64
#define DIN   384
#define L_    197
#define N_    16
#define TS    8            // time-steps per tile
#define NFULL 24           // full tiles: t = 0..191
#define T0TAIL 189         // tail staged at 189; compute li=3..7 (t=192..196)

// LDS word (float) layout per block:
//  buf b at b*BUFW:  A: 8 grp-pair blocks x 264 words (1056B, 32B stagger pad)
//                    B: same at +BWB;  X[2][16][4] at +XW (128 words)
//  Cs (transposed C[t*16+n]) at CSW.
#define BUFW  4352
#define BWB   2112
#define XW    4224
#define CSW   8704
#define LDSW  (CSW + L_*N_)   // 11856 floats = 47424 B

typedef unsigned int u32as1 __attribute__((address_space(1)));
typedef unsigned int u32as3 __attribute__((address_space(3)));

__device__ __forceinline__ void gll16(const float* g, float* l) {
    __builtin_amdgcn_global_load_lds((const u32as1*)g, (u32as3*)l, 16, 0, 0);
}
__device__ __forceinline__ void gll4(const float* g, float* l) {
    __builtin_amdgcn_global_load_lds((const u32as1*)g, (u32as3*)l, 4, 0, 0);
}

// p += dpp_permuted(p); ctrl 0xB1 = quad_perm [1,0,3,2] (xor1), 0x4E = [2,3,0,1] (xor2)
#define DPPADD(p, C) do { \
    int _r = __builtin_amdgcn_update_dpp(0, __float_as_int(p), (C), 0xF, 0xF, true); \
    (p) += __int_as_float(_r); } while (0)

// stage one 8-step tile for all 16 pairs: 8 A-calls + 8 B-calls (1KB each,
// per-lane source covers 2 pairs) + 2 x-calls (width 4). 18 vm ops total.
__device__ __forceinline__ void stage_tile(const float* sA, const float* sB,
                                           const float* sX, float* ab, int t0) {
#pragma unroll
    for (int p = 0; p < 8; ++p) gll16(sA + p * (2 * L_ * N_) + t0 * N_, ab + p * 264);
#pragma unroll
    for (int p = 0; p < 8; ++p) gll16(sB + p * (2 * L_ * N_) + t0 * N_, ab + BWB + p * 264);
    gll4(sX + t0 + 0, ab + XW + 0);
    gll4(sX + t0 + 4, ab + XW + 64);
}

__global__ __launch_bounds__(64, 1)
void ssm_dma(const float* __restrict__ x, const float* __restrict__ dA,
             const float* __restrict__ dB, const float* __restrict__ C,
             const float* __restrict__ D, float* __restrict__ y)
{
    __shared__ __align__(16) float lds[LDSW];

    const int tid = threadIdx.x;        // 0..63, one wave
    const int b   = blockIdx.y;
    const int d0  = blockIdx.x * 16;
    const int g   = tid >> 2;           // pair 0..15
    const int q   = tid & 3;            // 4-state slice within pair

    // ---- stage Cs transposed: lds[CSW + t*16 + n] = C[b,n,t]  (once per block)
    const float* Cg = C + (size_t)b * (N_ * L_);
    for (int i = tid; i < N_ * L_; i += 64) {
        const int n = i / L_;
        const int t = i - n * L_;
        lds[CSW + t * N_ + n] = Cg[i];
    }
    __syncthreads();

    const int bd0 = b * DIN + d0;
    // per-lane DMA source bases
    const float* sA = dA + (size_t)(bd0 + (tid >> 5)) * (L_ * N_) + (tid & 31) * 4;
    const float* sB = dB + (size_t)(bd0 + (tid >> 5)) * (L_ * N_) + (tid & 31) * 4;
    const float* sX = x  + (size_t)(bd0 + g) * L_ + q;
    float*      pyL = y  + (size_t)(bd0 + g) * L_;
    const float  Dd = D[d0 + g];

    // per-lane LDS read bases (float words)
    const int abL = (g >> 1) * 264 + (g & 1) * 128 + q * 4;
    const int csL = CSW + q * 4;
    const int xL  = XW + g * 4;

    float h0 = 0.f, h1 = 0.f, h2 = 0.f, h3 = 0.f, ya = 0.f, yb = 0.f;

#define STEP(li, ABB, CSB, XB) do { \
    const float4 a4 = *(const float4*)(lds + (ABB) + (li) * 16); \
    const float4 g4 = *(const float4*)(lds + (ABB) + BWB + (li) * 16); \
    const float4 c4 = *(const float4*)(lds + (CSB) + (li) * 16); \
    const float xv  = lds[(XB) + ((li) >> 2) * 64 + ((li) & 3)]; \
    h0 = fmaf(a4.x, h0, g4.x * xv); \
    h1 = fmaf(a4.y, h1, g4.y * xv); \
    h2 = fmaf(a4.z, h2, g4.z * xv); \
    h3 = fmaf(a4.w, h3, g4.w * xv); \
    float p = fmaf(h0, c4.x, fmaf(h1, c4.y, fmaf(h2, c4.z, h3 * c4.w))); \
    DPPADD(p, 0xB1); \
    DPPADD(p, 0x4E); \
    const float yt = fmaf(xv, Dd, p); \
    if (((li) & 3) == q) { if ((li) < 4) ya = yt; else yb = yt; } \
} while (0)

    stage_tile(sA, sB, sX, lds, 0);                       // tile 0 -> buf 0
    for (int k = 0; k < NFULL; ++k) {
        const int tn = (k + 1 < NFULL) ? (k + 1) * TS : T0TAIL;
        stage_tile(sA, sB, sX, lds + ((k + 1) & 1) * BUFW, tn);
        asm volatile("s_waitcnt vmcnt(18)" ::: "memory");  // tile k resident; k+1 in flight
        const int ABB = (k & 1) * BUFW + abL;
        const int CSB = csL + k * TS * N_;
        const int XB  = (k & 1) * BUFW + xL;
        const int t0  = k * TS;
        STEP(0, ABB, CSB, XB); STEP(1, ABB, CSB, XB);
        STEP(2, ABB, CSB, XB); STEP(3, ABB, CSB, XB);
        STEP(4, ABB, CSB, XB); STEP(5, ABB, CSB, XB);
        STEP(6, ABB, CSB, XB); STEP(7, ABB, CSB, XB);
        pyL[t0 + q]     = ya;          // 8 outputs/pair/tile, 2 stores/lane
        pyL[t0 + 4 + q] = yb;
    }
    asm volatile("s_waitcnt vmcnt(0)" ::: "memory");
    {   // tail: buf 0, staged at t0=189, compute t=192..196
        const int ABB = abL;
        const int CSB = csL + T0TAIL * N_;
        const int XB  = xL;
        STEP(3, ABB, CSB, XB); STEP(4, ABB, CSB, XB); STEP(5, ABB, CSB, XB);
        STEP(6, ABB, CSB, XB); STEP(7, ABB, CSB, XB);
        if (q == 3) pyL[192] = ya;
        pyL[193 + q] = yb;
    }
#undef STEP
}

extern "C" void kernel_launch(void* const* d_in, const int* in_sizes, int n_in,
                              void* d_out, int out_size, void* d_ws, size_t ws_size,
                              hipStream_t stream) {
    const float* x  = (const float*)d_in[0];
    const float* dA = (const float*)d_in[1];
    const float* dB = (const float*)d_in[2];
    const float* C  = (const float*)d_in[3];
    const float* D  = (const float*)d_in[4];
    float* y = (float*)d_out;

    dim3 grid(DIN / 16, B_);   // (24, 64) = 1536 blocks, 3/CU, 2 exact epochs
    dim3 block(64);            // 1 wave
    ssm_dma<<<grid, block, 0, stream>>>(x, dA, dB, C, D, y);
}

// Round 5
// 146.748 us; speedup vs baseline: 1.1092x; 1.0153x over previous
//
#include <hip/hip_runtime.h>

// Selective scan (Mamba-style), fp32.
// x:(B,d,L) dA/dB:(B,d,L,n) C:(B,n,L) D:(d,) -> y:(B,d,L);  B=64 d=384 L=197 n=16.
//
// Round-5: lane-per-state (16 lanes per (b,d)) -> 6144 waves = 24 waves/CU,
// combined with an explicit depth-1 double-buffered prefetch of 8-step bodies
// (16 scalar loads = 4KB/wave in flight, pinned with sched_barrier(0)).
// x and C staged LINEARLY in LDS (conflict-free reads: bank (5n+t)%32).
// Reduction: 2 DPP quad-perm adds + 2 shuffles. Outputs via cndmask tree.

#define B_   64
#define DIN  384
#define L_   197
#define N_   16
#define NB   24      // full 8-step bodies (t=0..191); tail t=192..196

#define DPPADD(p, C) do { \
    int _r = __builtin_amdgcn_update_dpp(0, __float_as_int(p), (C), 0xF, 0xF, true); \
    (p) += __int_as_float(_r); } while (0)

__global__ __launch_bounds__(256, 8)
void ssm_scan16(const float* __restrict__ x, const float* __restrict__ dA,
                const float* __restrict__ dB, const float* __restrict__ C,
                const float* __restrict__ D, float* __restrict__ y)
{
    __shared__ float Cs[N_ * L_];   // linear: Cs[n*L_ + t] = C[b,n,t]
    __shared__ float Xs[16 * L_];   // linear: Xs[g*L_ + t] = x[b,d0+g,t]

    const int tid = threadIdx.x;
    const int b   = blockIdx.y;
    const int d0  = blockIdx.x * 16;

    // linear staging, fully coalesced, no transpose -> no bank conflicts
    const float* Cg = C + (size_t)b * (N_ * L_);
    for (int i = tid; i < N_ * L_; i += 256) Cs[i] = Cg[i];
    const float* Xg = x + ((size_t)b * DIN + d0) * L_;
    for (int i = tid; i < 16 * L_; i += 256) Xs[i] = Xg[i];
    __syncthreads();

    const int g = tid >> 4;          // group = one (b,d), 16 per block
    const int n = tid & 15;          // state index
    const size_t bd = (size_t)b * DIN + d0 + g;

    const float* pA = dA + bd * (size_t)(L_ * N_) + n;   // elem t at pA[t*16]
    const float* pG = dB + bd * (size_t)(L_ * N_) + n;
    float*      pyL = y + bd * L_;
    const float  Dd = D[d0 + g];
    const float* CsL = Cs + n * L_;
    const float* XsL = Xs + g * L_;

    float h = 0.f;

    // named double buffers (PA/PG and QA/QG), 8 steps each
    float PA0,PA1,PA2,PA3,PA4,PA5,PA6,PA7, PG0,PG1,PG2,PG3,PG4,PG5,PG6,PG7;
    float QA0,QA1,QA2,QA3,QA4,QA5,QA6,QA7, QG0,QG1,QG2,QG3,QG4,QG5,QG6,QG7;

#define LOADB(Pa, Pg, t0) do { \
    Pa##0=pA[((t0)+0)*N_]; Pa##1=pA[((t0)+1)*N_]; Pa##2=pA[((t0)+2)*N_]; Pa##3=pA[((t0)+3)*N_]; \
    Pa##4=pA[((t0)+4)*N_]; Pa##5=pA[((t0)+5)*N_]; Pa##6=pA[((t0)+6)*N_]; Pa##7=pA[((t0)+7)*N_]; \
    Pg##0=pG[((t0)+0)*N_]; Pg##1=pG[((t0)+1)*N_]; Pg##2=pG[((t0)+2)*N_]; Pg##3=pG[((t0)+3)*N_]; \
    Pg##4=pG[((t0)+4)*N_]; Pg##5=pG[((t0)+5)*N_]; Pg##6=pG[((t0)+6)*N_]; Pg##7=pG[((t0)+7)*N_]; \
} while (0)

#define ST(Pa, Pg, t0, j, yv) do { \
    const float xv = XsL[(t0)+(j)]; \
    h = fmaf(Pa##j, h, Pg##j * xv); \
    float p = h * CsL[(t0)+(j)]; \
    DPPADD(p, 0xB1);   /* xor1 quad_perm [1,0,3,2] */ \
    DPPADD(p, 0x4E);   /* xor2 quad_perm [2,3,0,1] */ \
    p += __shfl_xor(p, 4); \
    p += __shfl_xor(p, 8); \
    yv = fmaf(xv, Dd, p); \
} while (0)

#define BODY(Pa, Pg, t0) do { \
    float y0,y1,y2,y3,y4,y5,y6,y7; \
    ST(Pa,Pg,t0,0,y0); ST(Pa,Pg,t0,1,y1); ST(Pa,Pg,t0,2,y2); ST(Pa,Pg,t0,3,y3); \
    ST(Pa,Pg,t0,4,y4); ST(Pa,Pg,t0,5,y5); ST(Pa,Pg,t0,6,y6); ST(Pa,Pg,t0,7,y7); \
    const float v0=(n&1)?y1:y0, v1=(n&1)?y3:y2, v2=(n&1)?y5:y4, v3=(n&1)?y7:y6; \
    const float w0=(n&2)?v1:v0, w1=(n&2)?v3:v2; \
    if (n < 8) pyL[(t0) + n] = (n&4)?w1:w0; \
} while (0)

    LOADB(PA, PG, 0);
    for (int k = 0; k < NB; k += 2) {
        const int tq = (k + 1) * 8;
        LOADB(QA, QG, tq);                      // prefetch body k+1
        __builtin_amdgcn_sched_barrier(0);      // pin: loads stay above compute
        BODY(PA, PG, k * 8);                    // compute body k
        if (k + 2 < NB) {
            LOADB(PA, PG, (k + 2) * 8);         // prefetch body k+2
        } else {
            // prefetch the 5-step tail into PA0..4/PG0..4 (t=192..196)
            PA0=pA[192*N_]; PA1=pA[193*N_]; PA2=pA[194*N_]; PA3=pA[195*N_]; PA4=pA[196*N_];
            PG0=pG[192*N_]; PG1=pG[193*N_]; PG2=pG[194*N_]; PG3=pG[195*N_]; PG4=pG[196*N_];
        }
        __builtin_amdgcn_sched_barrier(0);
        BODY(QA, QG, tq);                       // compute body k+1
    }

    // tail: t = 192..196 from PA0..4/PG0..4
    {
        float y0,y1,y2,y3,y4;
        ST(PA,PG,192,0,y0); ST(PA,PG,192,1,y1); ST(PA,PG,192,2,y2);
        ST(PA,PG,192,3,y3); ST(PA,PG,192,4,y4);
        const float v0=(n&1)?y1:y0, v1=(n&1)?y3:y2;
        const float w0=(n&2)?v1:v0;
        const float val=(n&4)?y4:w0;
        if (n < 5) pyL[192 + n] = val;
    }
#undef BODY
#undef ST
#undef LOADB
}

extern "C" void kernel_launch(void* const* d_in, const int* in_sizes, int n_in,
                              void* d_out, int out_size, void* d_ws, size_t ws_size,
                              hipStream_t stream) {
    const float* x  = (const float*)d_in[0];
    const float* dA = (const float*)d_in[1];
    const float* dB = (const float*)d_in[2];
    const float* C  = (const float*)d_in[3];
    const float* D  = (const float*)d_in[4];
    float* y = (float*)d_out;

    dim3 grid(DIN / 16, B_);   // (24, 64) = 1536 blocks; 6 blocks/CU, 24 waves/CU
    dim3 block(256);
    ssm_scan16<<<grid, block, 0, stream>>>(x, dA, dB, C, D, y);
}